// Round 1
// 5133.644 us; speedup vs baseline: 2.1107x; 2.1107x over previous
//
#include <hip/hip_runtime.h>
#include <stdint.h>

typedef unsigned short ushortT;
typedef __bf16 bf16_t;
typedef __bf16 bf16x8 __attribute__((ext_vector_type(8)));
typedef float  f32x4  __attribute__((ext_vector_type(4)));

constexpr int N_LAYER = 6;
constexpr int N_HEAD  = 12;
constexpr int HEAD_D  = 64;
constexpr int N_EMB   = 768;
constexpr int N_VOCAB = 32000;
constexpr int N_B     = 2;
constexpr int N_T     = 1024;
constexpr int N_M     = N_B * N_T;      // 2048
constexpr int QKVW    = 3 * N_EMB;      // 2304
constexpr float LN_EPS = 1e-5f;
constexpr float ATT_SCALE = 0.03608439182435161f; // 768^-0.5

__device__ __forceinline__ float us2f(ushortT u) {
    union { unsigned int i; float f; } c; c.i = ((unsigned int)u) << 16; return c.f;
}
__device__ __forceinline__ ushortT f2b(float f) {  // RNE fp32 -> bf16 bits
    union { float f; unsigned int u; } c; c.f = f;
    unsigned int u = c.u;
    return (ushortT)((u + 0x7fffu + ((u >> 16) & 1u)) >> 16);
}
// Dual-dtype scalar load: isf=1 -> fp32 buffer, else bf16 bits.
__device__ __forceinline__ float ldw(const void* p, int isf, size_t i) {
    if (isf) return ((const float*)p)[i];
    return us2f(((const ushortT*)p)[i]);
}
// async global->LDS, 16B per lane. lds base must be wave-uniform.
__device__ __forceinline__ void gload16(const void* g, void* l) {
    __builtin_amdgcn_global_load_lds(
        (const unsigned int __attribute__((address_space(1)))*)g,
        (unsigned int __attribute__((address_space(3)))*)l, 16, 0, 0);
}

// ---------------- dtype detection (unchanged) ----------------
__global__ __launch_bounds__(256) void detect_kernel(const unsigned int* __restrict__ w,
                                                     int* __restrict__ flag)
{
    __shared__ int red[256];
    int cnt = 0;
    for (int i = threadIdx.x; i < 4096; i += 256) {
        unsigned int u = w[i];
        float flo = us2f((ushortT)(u & 0xffffu));
        float fhi = us2f((ushortT)(u >> 16));
        if (!(fabsf(flo) < 0.5f)) cnt++;
        if (!(fabsf(fhi) < 0.5f)) cnt++;
    }
    red[threadIdx.x] = cnt;
    __syncthreads();
    for (int off = 128; off > 0; off >>= 1) {
        if (threadIdx.x < off) red[threadIdx.x] += red[threadIdx.x + off];
        __syncthreads();
    }
    if (threadIdx.x == 0) flag[0] = (red[0] > 64) ? 1 : 0;
}

// ---------------- embedding ----------------
__global__ __launch_bounds__(256) void embed_kernel(const int* __restrict__ x,
        const void* __restrict__ tok, const void* __restrict__ pos,
        const int* __restrict__ flag, float* __restrict__ h)
{
    const int isf = *flag;
    int idx = blockIdx.x * 256 + threadIdx.x;
    if (idx >= N_M * N_EMB) return;
    int m = idx / N_EMB, c = idx - m * N_EMB;
    int t = m & (N_T - 1);
    int tokid = x[m];
    h[idx] = ldw(tok, isf, (size_t)tokid * N_EMB + c) + ldw(pos, isf, (size_t)t * N_EMB + c);
}

// ---------------- layernorm -> bf16 hi/lo pair ----------------
__global__ __launch_bounds__(256) void ln_kernel(const float* __restrict__ in,
        const void* __restrict__ g, const void* __restrict__ b, size_t gofs,
        const int* __restrict__ flag, ushortT* __restrict__ outHi, ushortT* __restrict__ outLo)
{
    __shared__ float red[256];
    const int isf = *flag;
    const int tid = threadIdx.x;
    const float* row = in + (size_t)blockIdx.x * N_EMB;
    float v0 = row[tid], v1 = row[tid + 256], v2 = row[tid + 512];
    red[tid] = v0 + v1 + v2;
    __syncthreads();
    for (int off = 128; off > 0; off >>= 1) {
        if (tid < off) red[tid] += red[tid + off];
        __syncthreads();
    }
    float mean = red[0] * (1.0f / N_EMB);
    __syncthreads();
    float d0 = v0 - mean, d1 = v1 - mean, d2 = v2 - mean;
    red[tid] = d0 * d0 + d1 * d1 + d2 * d2;
    __syncthreads();
    for (int off = 128; off > 0; off >>= 1) {
        if (tid < off) red[tid] += red[tid + off];
        __syncthreads();
    }
    float inv = rsqrtf(red[0] * (1.0f / N_EMB) + LN_EPS);
    size_t ob = (size_t)blockIdx.x * N_EMB;
    float dd[3] = {d0, d1, d2};
    #pragma unroll
    for (int e = 0; e < 3; e++) {
        int c = tid + e * 256;
        float v = dd[e] * inv * ldw(g, isf, gofs + c) + ldw(b, isf, gofs + c);
        ushortT hb = f2b(v);
        outHi[ob + c] = hb;
        outLo[ob + c] = f2b(v - us2f(hb));
    }
}

// ---------------- weight convert+transpose: out[n][k] (bf16) = src[k][n] ----------------
__global__ __launch_bounds__(256) void conv_t(const void* __restrict__ src, size_t sofs,
        const int* __restrict__ flag, ushortT* __restrict__ out, int K, int N)
{
    __shared__ float t[32][33];
    const int isf = *flag;
    const int n0 = blockIdx.x * 32, k0 = blockIdx.y * 32;
    const int tx = threadIdx.x & 31, ty = threadIdx.x >> 5;
    #pragma unroll
    for (int kk = ty; kk < 32; kk += 8)
        t[kk][tx] = ldw(src, isf, sofs + (size_t)(k0 + kk) * N + n0 + tx);
    __syncthreads();
    #pragma unroll
    for (int nn = ty; nn < 32; nn += 8)
        out[(size_t)(n0 + nn) * K + k0 + tx] = f2b(t[tx][nn]);
}

// qkv weights: out[n][k], n = which*768 + h*64 + d ; src Wq/Wk/Wv (L,H,C,D)
__global__ __launch_bounds__(256) void conv_qkv(const void* __restrict__ Wq,
        const void* __restrict__ Wk, const void* __restrict__ Wv, size_t wofs,
        const int* __restrict__ flag, ushortT* __restrict__ out)
{
    __shared__ float t[32][33];
    const int isf = *flag;
    const int n0 = blockIdx.x * 32, k0 = blockIdx.y * 32;
    const int which = n0 / N_EMB, rem = n0 - which * N_EMB;
    const int h = rem >> 6, d0 = rem & 63;
    const void* src = (which == 0) ? Wq : (which == 1 ? Wk : Wv);
    const size_t base = wofs + (size_t)h * N_EMB * HEAD_D;
    const int tx = threadIdx.x & 31, ty = threadIdx.x >> 5;
    #pragma unroll
    for (int kk = ty; kk < 32; kk += 8)
        t[kk][tx] = ldw(src, isf, base + (size_t)(k0 + kk) * HEAD_D + d0 + tx);
    __syncthreads();
    #pragma unroll
    for (int nn = ty; nn < 32; nn += 8)
        out[(size_t)(n0 + nn) * N_EMB + k0 + tx] = f2b(t[tx][nn]);
}

// ---------------- MFMA GEMM: C = (Ahi+Alo) * B^T_staged ----------------
// A: M x K bf16 hi/lo (row-major, k-contig). Bw: [N][K] bf16 (k-contig).
// 256 threads = 4 waves, wave quadrant = (BM/2)x(BN/2). BK=64.
// LDS layout [8][rows][8]: chunk c holds k = kt+c*8 .. +7 for all rows, 16B/row.
template<int BM, int BN>
__global__ __launch_bounds__(256, 2) void gemm_mfma(
    const ushortT* __restrict__ Ahi, const ushortT* __restrict__ Alo,
    const ushortT* __restrict__ Bw,
    const void* __restrict__ bias, size_t biasOfs,
    const float* resid,
    float* outF, ushortT* outHi, ushortT* outLo, void* outFinal,
    const int* __restrict__ flag, int Ndim, int K, int relu)
{
    constexpr int MF = BM / 32, NF = BN / 32;
    __shared__ bf16_t Ah[8][BM][8];
    __shared__ bf16_t Al[8][BM][8];
    __shared__ bf16_t Bs[8][BN][8];
    const int tid = threadIdx.x;
    const int lane = tid & 63, w = tid >> 6;
    const int l15 = lane & 15, lg = lane >> 4;
    const int m0 = blockIdx.x * BM, n0 = blockIdx.y * BN;
    const int m_w = (w >> 1) * (BM / 2), n_w = (w & 1) * (BN / 2);
    const int isf = *flag;

    constexpr int CA = BM / 8, CB = BN / 8, TOT = 2 * CA + CB, PW = TOT / 4;

    f32x4 acc[MF][NF];
    #pragma unroll
    for (int i = 0; i < MF; i++)
        #pragma unroll
        for (int j = 0; j < NF; j++) { f32x4 z = {0.f, 0.f, 0.f, 0.f}; acc[i][j] = z; }

    for (int kt = 0; kt < K; kt += 64) {
        __syncthreads();                      // previous compute done reading LDS
        #pragma unroll
        for (int q0 = 0; q0 < PW; ++q0) {
            const int q = w * PW + q0;
            const bf16_t* dst; const ushortT* src;
            if (q < CA) {
                const int c = q & 7, hf = q >> 3;
                dst = &Ah[c][hf * 64][0];
                src = Ahi + (size_t)(m0 + hf * 64 + lane) * K + (kt + c * 8);
            } else if (q < 2 * CA) {
                const int qq = q - CA, c = qq & 7, hf = qq >> 3;
                dst = &Al[c][hf * 64][0];
                src = Alo + (size_t)(m0 + hf * 64 + lane) * K + (kt + c * 8);
            } else {
                const int qq = q - 2 * CA, c = qq & 7, hf = qq >> 3;
                dst = &Bs[c][hf * 64][0];
                src = Bw + (size_t)(n0 + hf * 64 + lane) * K + (kt + c * 8);
            }
            gload16((const void*)src, (void*)dst);
        }
        __syncthreads();                      // drains vmcnt -> LDS ready
        #pragma unroll
        for (int kk = 0; kk < 2; ++kk) {
            const int cb = kk * 4 + lg;
            bf16x8 bv[NF];
            #pragma unroll
            for (int j = 0; j < NF; ++j)
                bv[j] = *(const bf16x8*)(&Bs[cb][n_w + 16 * j + l15][0]);
            #pragma unroll
            for (int i = 0; i < MF; ++i) {
                bf16x8 ah = *(const bf16x8*)(&Ah[cb][m_w + 16 * i + l15][0]);
                bf16x8 al = *(const bf16x8*)(&Al[cb][m_w + 16 * i + l15][0]);
                #pragma unroll
                for (int j = 0; j < NF; ++j) {
                    acc[i][j] = __builtin_amdgcn_mfma_f32_16x16x32_bf16(ah, bv[j], acc[i][j], 0, 0, 0);
                    acc[i][j] = __builtin_amdgcn_mfma_f32_16x16x32_bf16(al, bv[j], acc[i][j], 0, 0, 0);
                }
            }
        }
    }
    // epilogue: C/D layout col=lane&15, row=(lane>>4)*4+reg (m89-verified)
    #pragma unroll
    for (int i = 0; i < MF; ++i) {
        #pragma unroll
        for (int r = 0; r < 4; ++r) {
            const int row = m0 + m_w + 16 * i + lg * 4 + r;
            const size_t rb = (size_t)row * Ndim;
            #pragma unroll
            for (int j = 0; j < NF; ++j) {
                const int col = n0 + n_w + 16 * j + l15;
                float v = acc[i][j][r];
                if (bias)  v += ldw(bias, isf, biasOfs + col);
                if (resid) v += resid[rb + col];
                if (relu)  v = fmaxf(v, 0.0f);
                if (outF)  outF[rb + col] = v;
                if (outHi) {
                    ushortT hb = f2b(v);
                    outHi[rb + col] = hb;
                    outLo[rb + col] = f2b(v - us2f(hb));
                }
                if (outFinal) {
                    if (isf) ((float*)outFinal)[rb + col] = v;
                    else     ((ushortT*)outFinal)[rb + col] = f2b(v);
                }
            }
        }
    }
}

// ---------------- flash attention (fp32 SIMT), qkv input (M x 2304), bf16 hi/lo output ----------------
__global__ __launch_bounds__(256) void attn_kernel(
    const float* __restrict__ qkv, ushortT* __restrict__ oHi, ushortT* __restrict__ oLo)
{
    __shared__ float Qs[64][68];
    __shared__ float KS[64][68];   // K tile, then reused for P
    __shared__ float Vs[64][68];
    __shared__ float mrow[64], lrow[64], arow[64];
    const int tq = blockIdx.x;
    const int h = blockIdx.y, b = blockIdx.z;
    const int tid = threadIdx.x;
    const int tx = tid & 15, ty = tid >> 4;
    const float* qb = qkv + (size_t)b * N_T * QKVW + h * HEAD_D;
    const float* kb = qb + N_EMB;
    const float* vb = qb + 2 * N_EMB;

    const int rr = tid >> 2;
    const int cc = (tid & 3) * 16;
    {
        const float* src = qb + (size_t)(tq * 64 + rr) * QKVW + cc;
        #pragma unroll
        for (int j = 0; j < 16; j += 4)
            *(float4*)&Qs[rr][cc + j] = *(const float4*)(src + j);
    }
    if (tid < 64) { mrow[tid] = -1e30f; lrow[tid] = 0.0f; }
    float oa[4][4] = {};

    for (int kt = 0; kt <= tq; kt++) {
        __syncthreads();
        {
            const float* ks = kb + (size_t)(kt * 64 + rr) * QKVW + cc;
            const float* vs = vb + (size_t)(kt * 64 + rr) * QKVW + cc;
            #pragma unroll
            for (int j = 0; j < 16; j += 4) {
                *(float4*)&KS[rr][cc + j] = *(const float4*)(ks + j);
                *(float4*)&Vs[rr][cc + j] = *(const float4*)(vs + j);
            }
        }
        __syncthreads();
        float s[4][4] = {};
        #pragma unroll
        for (int kk = 0; kk < 64; kk += 4) {
            float4 qv[4], kv[4];
            #pragma unroll
            for (int i = 0; i < 4; i++) qv[i] = *(const float4*)&Qs[ty * 4 + i][kk];
            #pragma unroll
            for (int j = 0; j < 4; j++) kv[j] = *(const float4*)&KS[tx * 4 + j][kk];
            #pragma unroll
            for (int i = 0; i < 4; i++)
                #pragma unroll
                for (int j = 0; j < 4; j++)
                    s[i][j] += qv[i].x * kv[j].x + qv[i].y * kv[j].y +
                               qv[i].z * kv[j].z + qv[i].w * kv[j].w;
        }
        const int qr0 = tq * 64 + ty * 4, kc0 = kt * 64 + tx * 4;
        #pragma unroll
        for (int i = 0; i < 4; i++)
            #pragma unroll
            for (int j = 0; j < 4; j++)
                s[i][j] = (kc0 + j <= qr0 + i) ? s[i][j] * ATT_SCALE : -1e30f;
        __syncthreads();
        #pragma unroll
        for (int i = 0; i < 4; i++)
            #pragma unroll
            for (int j = 0; j < 4; j++)
                KS[ty * 4 + i][tx * 4 + j] = s[i][j];
        __syncthreads();
        {
            const int r = tid >> 2, part = tid & 3;
            const int c0 = part * 16;
            float mo = mrow[r];
            float mx = -1e30f;
            #pragma unroll
            for (int c = 0; c < 16; c++) mx = fmaxf(mx, KS[r][c0 + c]);
            mx = fmaxf(mx, __shfl_xor(mx, 1));
            mx = fmaxf(mx, __shfl_xor(mx, 2));
            mx = fmaxf(mx, mo);
            float sum = 0.0f;
            #pragma unroll
            for (int c = 0; c < 16; c++) {
                float p = __expf(KS[r][c0 + c] - mx);
                KS[r][c0 + c] = p;
                sum += p;
            }
            sum += __shfl_xor(sum, 1);
            sum += __shfl_xor(sum, 2);
            if (part == 0) {
                float al = __expf(mo - mx);
                mrow[r] = mx;
                lrow[r] = lrow[r] * al + sum;
                arow[r] = al;
            }
        }
        __syncthreads();
        #pragma unroll
        for (int i = 0; i < 4; i++) {
            float al = arow[ty * 4 + i];
            #pragma unroll
            for (int j = 0; j < 4; j++) oa[i][j] *= al;
        }
        #pragma unroll
        for (int ss = 0; ss < 64; ss += 4) {
            float4 p4[4], v4[4];
            #pragma unroll
            for (int i = 0; i < 4; i++) p4[i] = *(const float4*)&KS[ty * 4 + i][ss];
            #pragma unroll
            for (int s2 = 0; s2 < 4; s2++) v4[s2] = *(const float4*)&Vs[ss + s2][tx * 4];
            #pragma unroll
            for (int i = 0; i < 4; i++) {
                float4 P = p4[i];
                oa[i][0] += P.x * v4[0].x + P.y * v4[1].x + P.z * v4[2].x + P.w * v4[3].x;
                oa[i][1] += P.x * v4[0].y + P.y * v4[1].y + P.z * v4[2].y + P.w * v4[3].y;
                oa[i][2] += P.x * v4[0].z + P.y * v4[1].z + P.z * v4[2].z + P.w * v4[3].z;
                oa[i][3] += P.x * v4[0].w + P.y * v4[1].w + P.z * v4[2].w + P.w * v4[3].w;
            }
        }
    }
    #pragma unroll
    for (int i = 0; i < 4; i++) {
        int r = ty * 4 + i;
        int t = tq * 64 + r;
        float invl = 1.0f / lrow[r];
        size_t ob = ((size_t)(b * N_T + t)) * N_EMB + h * HEAD_D + tx * 4;
        #pragma unroll
        for (int jj = 0; jj < 4; jj++) {
            float vv = oa[i][jj] * invl;
            ushortT hb = f2b(vv);
            oHi[ob + jj] = hb;
            oLo[ob + jj] = f2b(vv - us2f(hb));
        }
    }
}

extern "C" void kernel_launch(void* const* d_in, const int* in_sizes, int n_in,
                              void* d_out, int out_size, void* d_ws, size_t ws_size,
                              hipStream_t stream)
{
    const int*  x    = (const int*) d_in[0];
    const void* tok  = d_in[1];
    const void* pos  = d_in[2];
    const void* Wq   = d_in[3];
    const void* Wk   = d_in[4];
    const void* Wv   = d_in[5];
    const void* Wo   = d_in[6];
    const void* bo   = d_in[7];
    const void* ln1g = d_in[8];
    const void* ln1b = d_in[9];
    const void* ln2g = d_in[10];
    const void* ln2b = d_in[11];
    const void* W1   = d_in[12];
    const void* b1   = d_in[13];
    const void* W2   = d_in[14];
    const void* b2   = d_in[15];
    const void* lnfg = d_in[16];
    const void* lnfb = d_in[17];
    const void* Wh   = d_in[18];
    const void* bh   = d_in[19];

    float* ws = (float*)d_ws;
    int* flag = (int*)ws;
    const size_t MC = (size_t)N_M * N_EMB;           // 1,572,864
    float*   h    = ws + 64;                         // MC fp32
    ushortT* aHi  = (ushortT*)(h + MC);              // MC bf16
    ushortT* aLo  = aHi + MC;                        // MC bf16
    float*   qkvF = (float*)(aLo + MC);              // region: max(3*MC f32, 8*MC bf16) = 4*MC f32
    ushortT* ffhHi = (ushortT*)qkvF;                 // 4*MC bf16 (aliases qkvF; qkv dead by FFN)
    ushortT* ffhLo = ffhHi + 4 * MC;                 // 4*MC bf16
    ushortT* wstg = (ushortT*)(qkvF + 4 * MC);       // up to 32000*768 bf16 (49.2 MB)
    ushortT* wsQ  = wstg;                            // 2304*768
    ushortT* wsO  = wsQ  + (size_t)QKVW * N_EMB;     // 768*768
    ushortT* wsF1 = wsO  + (size_t)N_EMB * N_EMB;    // 3072*768
    ushortT* wsF2 = wsF1 + (size_t)N_EMB * 4 * N_EMB;// 768*3072

    detect_kernel<<<1, 256, 0, stream>>>((const unsigned int*)tok, flag);
    embed_kernel<<<(int)((MC + 255) / 256), 256, 0, stream>>>(x, tok, pos, flag, h);

    for (int l = 0; l < N_LAYER; l++) {
        ln_kernel<<<N_M, 256, 0, stream>>>(h, ln1g, ln1b, (size_t)l * N_EMB, flag, aHi, aLo);

        conv_qkv<<<dim3(QKVW / 32, N_EMB / 32), 256, 0, stream>>>(
            Wq, Wk, Wv, (size_t)l * N_HEAD * N_EMB * HEAD_D, flag, wsQ);
        gemm_mfma<128, 128><<<dim3(N_M / 128, QKVW / 128), 256, 0, stream>>>(
            aHi, aLo, wsQ, nullptr, 0, nullptr, qkvF, nullptr, nullptr, nullptr,
            flag, QKVW, N_EMB, 0);

        attn_kernel<<<dim3(N_T / 64, N_HEAD, N_B), 256, 0, stream>>>(qkvF, aHi, aLo);

        conv_t<<<dim3(N_EMB / 32, N_EMB / 32), 256, 0, stream>>>(
            Wo, (size_t)l * N_EMB * N_EMB, flag, wsO, N_EMB, N_EMB);
        gemm_mfma<64, 64><<<dim3(N_M / 64, N_EMB / 64), 256, 0, stream>>>(
            aHi, aLo, wsO, bo, (size_t)l * N_EMB, h, h, nullptr, nullptr, nullptr,
            flag, N_EMB, N_EMB, 0);

        ln_kernel<<<N_M, 256, 0, stream>>>(h, ln2g, ln2b, (size_t)l * N_EMB, flag, aHi, aLo);

        conv_t<<<dim3(4 * N_EMB / 32, N_EMB / 32), 256, 0, stream>>>(
            W1, (size_t)l * N_EMB * 4 * N_EMB, flag, wsF1, N_EMB, 4 * N_EMB);
        gemm_mfma<128, 128><<<dim3(N_M / 128, 4 * N_EMB / 128), 256, 0, stream>>>(
            aHi, aLo, wsF1, b1, (size_t)l * 4 * N_EMB, nullptr, nullptr, ffhHi, ffhLo, nullptr,
            flag, 4 * N_EMB, N_EMB, 1);

        conv_t<<<dim3(N_EMB / 32, 4 * N_EMB / 32), 256, 0, stream>>>(
            W2, (size_t)l * 4 * N_EMB * N_EMB, flag, wsF2, 4 * N_EMB, N_EMB);
        gemm_mfma<64, 64><<<dim3(N_M / 64, N_EMB / 64), 256, 0, stream>>>(
            ffhHi, ffhLo, wsF2, b2, (size_t)l * N_EMB, h, h, nullptr, nullptr, nullptr,
            flag, N_EMB, 4 * N_EMB, 0);
    }

    ln_kernel<<<N_M, 256, 0, stream>>>(h, lnfg, lnfb, 0, flag, aHi, aLo);

    conv_t<<<dim3(N_VOCAB / 32, N_EMB / 32), 256, 0, stream>>>(
        Wh, 0, flag, wstg, N_EMB, N_VOCAB);
    gemm_mfma<128, 128><<<dim3(N_M / 128, N_VOCAB / 128), 256, 0, stream>>>(
        aHi, aLo, wstg, bh, 0, nullptr, nullptr, nullptr, nullptr, d_out,
        flag, N_VOCAB, N_EMB, 0);
}

// Round 2
// 4363.477 us; speedup vs baseline: 2.4832x; 1.1765x over previous
//
#include <hip/hip_runtime.h>
#include <stdint.h>

typedef unsigned short ushortT;
typedef __bf16 bf16_t;
typedef __bf16 bf16x8 __attribute__((ext_vector_type(8)));
typedef float  f32x4  __attribute__((ext_vector_type(4)));

constexpr int N_LAYER = 6;
constexpr int N_HEAD  = 12;
constexpr int HEAD_D  = 64;
constexpr int N_EMB   = 768;
constexpr int N_VOCAB = 32000;
constexpr int N_B     = 2;
constexpr int N_T     = 1024;
constexpr int N_M     = N_B * N_T;      // 2048
constexpr int QKVW    = 3 * N_EMB;      // 2304
constexpr float LN_EPS = 1e-5f;
constexpr float ATT_SCALE = 0.03608439182435161f; // 768^-0.5

__device__ __forceinline__ float us2f(ushortT u) {
    union { unsigned int i; float f; } c; c.i = ((unsigned int)u) << 16; return c.f;
}
__device__ __forceinline__ ushortT f2b(float f) {  // RNE fp32 -> bf16 bits
    union { float f; unsigned int u; } c; c.f = f;
    unsigned int u = c.u;
    return (ushortT)((u + 0x7fffu + ((u >> 16) & 1u)) >> 16);
}
__device__ __forceinline__ float ldw(const void* p, int isf, size_t i) {
    if (isf) return ((const float*)p)[i];
    return us2f(((const ushortT*)p)[i]);
}
// async global->LDS, 16B per lane. lds base must be wave-uniform.
__device__ __forceinline__ void gload16(const void* g, void* l) {
    __builtin_amdgcn_global_load_lds(
        (const unsigned int __attribute__((address_space(1)))*)g,
        (unsigned int __attribute__((address_space(3)))*)l, 16, 0, 0);
}

// ---------------- dtype detection ----------------
__global__ __launch_bounds__(256) void detect_kernel(const unsigned int* __restrict__ w,
                                                     int* __restrict__ flag)
{
    __shared__ int red[256];
    int cnt = 0;
    for (int i = threadIdx.x; i < 4096; i += 256) {
        unsigned int u = w[i];
        float flo = us2f((ushortT)(u & 0xffffu));
        float fhi = us2f((ushortT)(u >> 16));
        if (!(fabsf(flo) < 0.5f)) cnt++;
        if (!(fabsf(fhi) < 0.5f)) cnt++;
    }
    red[threadIdx.x] = cnt;
    __syncthreads();
    for (int off = 128; off > 0; off >>= 1) {
        if (threadIdx.x < off) red[threadIdx.x] += red[threadIdx.x + off];
        __syncthreads();
    }
    if (threadIdx.x == 0) flag[0] = (red[0] > 64) ? 1 : 0;
}

// ---------------- embedding ----------------
__global__ __launch_bounds__(256) void embed_kernel(const int* __restrict__ x,
        const void* __restrict__ tok, const void* __restrict__ pos,
        const int* __restrict__ flag, float* __restrict__ h)
{
    const int isf = *flag;
    int idx = blockIdx.x * 256 + threadIdx.x;
    if (idx >= N_M * N_EMB) return;
    int m = idx / N_EMB, c = idx - m * N_EMB;
    int t = m & (N_T - 1);
    int tokid = x[m];
    h[idx] = ldw(tok, isf, (size_t)tokid * N_EMB + c) + ldw(pos, isf, (size_t)t * N_EMB + c);
}

// ---------------- layernorm -> single bf16, shuffle reduce ----------------
__global__ __launch_bounds__(256) void ln_kernel(const float* __restrict__ in,
        const void* __restrict__ g, const void* __restrict__ b, size_t gofs,
        const int* __restrict__ flag, ushortT* __restrict__ out)
{
    __shared__ float part[8];
    const int isf = *flag;
    const int tid = threadIdx.x, lane = tid & 63, w = tid >> 6;
    const float* row = in + (size_t)blockIdx.x * N_EMB;
    float v0 = row[tid], v1 = row[tid + 256], v2 = row[tid + 512];
    float s = v0 + v1 + v2;
    #pragma unroll
    for (int o = 32; o; o >>= 1) s += __shfl_xor(s, o);
    if (lane == 0) part[w] = s;
    __syncthreads();
    float mean = (part[0] + part[1] + part[2] + part[3]) * (1.0f / N_EMB);
    float d0 = v0 - mean, d1 = v1 - mean, d2 = v2 - mean;
    float q = d0 * d0 + d1 * d1 + d2 * d2;
    #pragma unroll
    for (int o = 32; o; o >>= 1) q += __shfl_xor(q, o);
    if (lane == 0) part[4 + w] = q;
    __syncthreads();
    float inv = rsqrtf((part[4] + part[5] + part[6] + part[7]) * (1.0f / N_EMB) + LN_EPS);
    size_t ob = (size_t)blockIdx.x * N_EMB;
    float dd[3] = {d0, d1, d2};
    #pragma unroll
    for (int e = 0; e < 3; e++) {
        int c = tid + e * 256;
        float v = dd[e] * inv * ldw(g, isf, gofs + c) + ldw(b, isf, gofs + c);
        out[ob + c] = f2b(v);
    }
}

// ---------------- bias prefill: h[m][c] += bias[c] ----------------
__global__ __launch_bounds__(256) void addbias_kernel(float* __restrict__ h,
        const void* __restrict__ bias, size_t bofs, const int* __restrict__ flag)
{
    const int isf = *flag;
    int idx = blockIdx.x * 256 + threadIdx.x;
    if (idx >= N_M * N_EMB) return;
    int m = idx / N_EMB, c = idx - m * N_EMB;
    h[idx] += ldw(bias, isf, bofs + c);
}

// ---------------- weight convert+transpose: out[n][k] (bf16) = src[k][n] ----------------
__global__ __launch_bounds__(256) void conv_t(const void* __restrict__ src, size_t sofs,
        const int* __restrict__ flag, ushortT* __restrict__ out, int K, int N)
{
    __shared__ float t[32][33];
    const int isf = *flag;
    const int n0 = blockIdx.x * 32, k0 = blockIdx.y * 32;
    const int tx = threadIdx.x & 31, ty = threadIdx.x >> 5;
    #pragma unroll
    for (int kk = ty; kk < 32; kk += 8)
        t[kk][tx] = ldw(src, isf, sofs + (size_t)(k0 + kk) * N + n0 + tx);
    __syncthreads();
    #pragma unroll
    for (int nn = ty; nn < 32; nn += 8)
        out[(size_t)(n0 + nn) * K + k0 + tx] = f2b(t[tx][nn]);
}

// qkv weights: out[n][k], n = which*768 + h*64 + d ; src Wq/Wk/Wv (L,H,C,D)
__global__ __launch_bounds__(256) void conv_qkv(const void* __restrict__ Wq,
        const void* __restrict__ Wk, const void* __restrict__ Wv, size_t wofs,
        const int* __restrict__ flag, ushortT* __restrict__ out)
{
    __shared__ float t[32][33];
    const int isf = *flag;
    const int n0 = blockIdx.x * 32, k0 = blockIdx.y * 32;
    const int which = n0 / N_EMB, rem = n0 - which * N_EMB;
    const int h = rem >> 6, d0 = rem & 63;
    const void* src = (which == 0) ? Wq : (which == 1 ? Wk : Wv);
    const size_t base = wofs + (size_t)h * N_EMB * HEAD_D;
    const int tx = threadIdx.x & 31, ty = threadIdx.x >> 5;
    #pragma unroll
    for (int kk = ty; kk < 32; kk += 8)
        t[kk][tx] = ldw(src, isf, base + (size_t)(k0 + kk) * HEAD_D + d0 + tx);
    __syncthreads();
    #pragma unroll
    for (int nn = ty; nn < 32; nn += 8)
        out[(size_t)(n0 + nn) * N_EMB + k0 + tx] = f2b(t[tx][nn]);
}

// ---------------- MFMA GEMM: C = A(bf16) * B^T_staged (bf16) ----------------
// A: M x K bf16 row-major. Bw: [N][K] bf16 (k-contig).
// 4 waves, wave quadrant (BM/2)x(BN/2). BK=64. Double-buffered LDS,
// one barrier per K-step: STAGE(next) -> compute(cur) -> barrier (drains vmcnt).
template<int BM, int BN>
__global__ __launch_bounds__(256) void gemm_mfma(
    const ushortT* __restrict__ A, const ushortT* __restrict__ Bw,
    const void* __restrict__ bias, size_t biasOfs,
    float* __restrict__ outF, ushortT* __restrict__ outH, void* outFinal,
    float* __restrict__ outAtomic,
    const int* __restrict__ flag, int Ndim, int K, int kspan, int relu)
{
    constexpr int MF = BM / 32, NF = BN / 32;
    constexpr int CA = BM / 8, CB = BN / 8, TOT = CA + CB, PW = TOT / 4;
    __shared__ bf16_t Ah[2][8][BM][8];
    __shared__ bf16_t Bs[2][8][BN][8];
    const int tid = threadIdx.x;
    const int lane = tid & 63, w = tid >> 6;
    const int l15 = lane & 15, lg = lane >> 4;

    // XCD-aware block swizzle (grids are multiples of 8)
    const int nxy = gridDim.x * gridDim.y;
    int id = blockIdx.x + gridDim.x * blockIdx.y;
    if ((nxy & 7) == 0) {
        const int per = nxy >> 3;
        id = (id & 7) * per + (id >> 3);
    }
    const int bx = id % gridDim.x, by = id / gridDim.x;
    const int m0 = bx * BM, n0 = by * BN;
    const int kt0 = blockIdx.z * kspan;
    const int nsteps = kspan / 64;
    const int isf = *flag;
    const int m_w = (w >> 1) * (BM / 2), n_w = (w & 1) * (BN / 2);

    auto STAGE = [&](int buf, int kt) {
        #pragma unroll
        for (int q0 = 0; q0 < PW; ++q0) {
            const int q = w * PW + q0;
            if (q < CA) {
                const int c = q & 7, hf = q >> 3;
                gload16(A + (size_t)(m0 + hf * 64 + lane) * K + kt + c * 8,
                        &Ah[buf][c][hf * 64][0]);
            } else {
                const int qq = q - CA, c = qq & 7, hf = qq >> 3;
                gload16(Bw + (size_t)(n0 + hf * 64 + lane) * K + kt + c * 8,
                        &Bs[buf][c][hf * 64][0]);
            }
        }
    };

    f32x4 acc[MF][NF];
    #pragma unroll
    for (int i = 0; i < MF; i++)
        #pragma unroll
        for (int j = 0; j < NF; j++) { f32x4 z = {0.f, 0.f, 0.f, 0.f}; acc[i][j] = z; }

    STAGE(0, kt0);
    __syncthreads();                  // compiler drains vmcnt(0) before barrier
    int cur = 0;
    for (int t = 0; t < nsteps; ++t) {
        if (t + 1 < nsteps) STAGE(cur ^ 1, kt0 + (t + 1) * 64);
        #pragma unroll
        for (int kk = 0; kk < 2; ++kk) {
            const int cb = kk * 4 + lg;
            bf16x8 bv[NF];
            #pragma unroll
            for (int j = 0; j < NF; ++j)
                bv[j] = *(const bf16x8*)(&Bs[cur][cb][n_w + 16 * j + l15][0]);
            #pragma unroll
            for (int i = 0; i < MF; ++i) {
                bf16x8 av = *(const bf16x8*)(&Ah[cur][cb][m_w + 16 * i + l15][0]);
                #pragma unroll
                for (int j = 0; j < NF; ++j)
                    acc[i][j] = __builtin_amdgcn_mfma_f32_16x16x32_bf16(av, bv[j], acc[i][j], 0, 0, 0);
            }
        }
        __syncthreads();              // drains staged loads for next tile + read-before-write
        cur ^= 1;
    }

    // epilogue: C/D layout col=lane&15, row=(lane>>4)*4+reg
    #pragma unroll
    for (int i = 0; i < MF; ++i) {
        #pragma unroll
        for (int r = 0; r < 4; ++r) {
            const int row = m0 + m_w + 16 * i + lg * 4 + r;
            const size_t rb = (size_t)row * Ndim;
            #pragma unroll
            for (int j = 0; j < NF; ++j) {
                const int col = n0 + n_w + 16 * j + l15;
                float v = acc[i][j][r];
                if (bias)  v += ldw(bias, isf, biasOfs + col);
                if (relu)  v = fmaxf(v, 0.0f);
                if (outAtomic) atomicAdd(&outAtomic[rb + col], v);
                if (outF)  outF[rb + col] = v;
                if (outH)  outH[rb + col] = f2b(v);
                if (outFinal) {
                    if (isf) ((float*)outFinal)[rb + col] = v;
                    else     ((ushortT*)outFinal)[rb + col] = f2b(v);
                }
            }
        }
    }
}

// ---------------- flash attention (fp32 SIMT), qkv input (M x 2304), bf16 out ----------------
__global__ __launch_bounds__(256) void attn_kernel(
    const float* __restrict__ qkv, ushortT* __restrict__ oH)
{
    __shared__ float Qs[64][68];
    __shared__ float KS[64][68];   // K tile, then reused for P
    __shared__ float Vs[64][68];
    __shared__ float mrow[64], lrow[64], arow[64];
    const int tq = blockIdx.x;
    const int h = blockIdx.y, b = blockIdx.z;
    const int tid = threadIdx.x;
    const int tx = tid & 15, ty = tid >> 4;
    const float* qb = qkv + (size_t)b * N_T * QKVW + h * HEAD_D;
    const float* kb = qb + N_EMB;
    const float* vb = qb + 2 * N_EMB;

    const int rr = tid >> 2;
    const int cc = (tid & 3) * 16;
    {
        const float* src = qb + (size_t)(tq * 64 + rr) * QKVW + cc;
        #pragma unroll
        for (int j = 0; j < 16; j += 4)
            *(float4*)&Qs[rr][cc + j] = *(const float4*)(src + j);
    }
    if (tid < 64) { mrow[tid] = -1e30f; lrow[tid] = 0.0f; }
    float oa[4][4] = {};

    for (int kt = 0; kt <= tq; kt++) {
        __syncthreads();
        {
            const float* ks = kb + (size_t)(kt * 64 + rr) * QKVW + cc;
            const float* vs = vb + (size_t)(kt * 64 + rr) * QKVW + cc;
            #pragma unroll
            for (int j = 0; j < 16; j += 4) {
                *(float4*)&KS[rr][cc + j] = *(const float4*)(ks + j);
                *(float4*)&Vs[rr][cc + j] = *(const float4*)(vs + j);
            }
        }
        __syncthreads();
        float s[4][4] = {};
        #pragma unroll
        for (int kk = 0; kk < 64; kk += 4) {
            float4 qv[4], kv[4];
            #pragma unroll
            for (int i = 0; i < 4; i++) qv[i] = *(const float4*)&Qs[ty * 4 + i][kk];
            #pragma unroll
            for (int j = 0; j < 4; j++) kv[j] = *(const float4*)&KS[tx * 4 + j][kk];
            #pragma unroll
            for (int i = 0; i < 4; i++)
                #pragma unroll
                for (int j = 0; j < 4; j++)
                    s[i][j] += qv[i].x * kv[j].x + qv[i].y * kv[j].y +
                               qv[i].z * kv[j].z + qv[i].w * kv[j].w;
        }
        const int qr0 = tq * 64 + ty * 4, kc0 = kt * 64 + tx * 4;
        #pragma unroll
        for (int i = 0; i < 4; i++)
            #pragma unroll
            for (int j = 0; j < 4; j++)
                s[i][j] = (kc0 + j <= qr0 + i) ? s[i][j] * ATT_SCALE : -1e30f;
        __syncthreads();
        #pragma unroll
        for (int i = 0; i < 4; i++)
            #pragma unroll
            for (int j = 0; j < 4; j++)
                KS[ty * 4 + i][tx * 4 + j] = s[i][j];
        __syncthreads();
        {
            const int r = tid >> 2, part = tid & 3;
            const int c0 = part * 16;
            float mo = mrow[r];
            float mx = -1e30f;
            #pragma unroll
            for (int c = 0; c < 16; c++) mx = fmaxf(mx, KS[r][c0 + c]);
            mx = fmaxf(mx, __shfl_xor(mx, 1));
            mx = fmaxf(mx, __shfl_xor(mx, 2));
            mx = fmaxf(mx, mo);
            float sum = 0.0f;
            #pragma unroll
            for (int c = 0; c < 16; c++) {
                float p = __expf(KS[r][c0 + c] - mx);
                KS[r][c0 + c] = p;
                sum += p;
            }
            sum += __shfl_xor(sum, 1);
            sum += __shfl_xor(sum, 2);
            if (part == 0) {
                float al = __expf(mo - mx);
                mrow[r] = mx;
                lrow[r] = lrow[r] * al + sum;
                arow[r] = al;
            }
        }
        __syncthreads();
        #pragma unroll
        for (int i = 0; i < 4; i++) {
            float al = arow[ty * 4 + i];
            #pragma unroll
            for (int j = 0; j < 4; j++) oa[i][j] *= al;
        }
        #pragma unroll
        for (int ss = 0; ss < 64; ss += 4) {
            float4 p4[4], v4[4];
            #pragma unroll
            for (int i = 0; i < 4; i++) p4[i] = *(const float4*)&KS[ty * 4 + i][ss];
            #pragma unroll
            for (int s2 = 0; s2 < 4; s2++) v4[s2] = *(const float4*)&Vs[ss + s2][tx * 4];
            #pragma unroll
            for (int i = 0; i < 4; i++) {
                float4 P = p4[i];
                oa[i][0] += P.x * v4[0].x + P.y * v4[1].x + P.z * v4[2].x + P.w * v4[3].x;
                oa[i][1] += P.x * v4[0].y + P.y * v4[1].y + P.z * v4[2].y + P.w * v4[3].y;
                oa[i][2] += P.x * v4[0].z + P.y * v4[1].z + P.z * v4[2].z + P.w * v4[3].z;
                oa[i][3] += P.x * v4[0].w + P.y * v4[1].w + P.z * v4[2].w + P.w * v4[3].w;
            }
        }
    }
    #pragma unroll
    for (int i = 0; i < 4; i++) {
        int r = ty * 4 + i;
        int t = tq * 64 + r;
        float invl = 1.0f / lrow[r];
        size_t ob = ((size_t)(b * N_T + t)) * N_EMB + h * HEAD_D + tx * 4;
        #pragma unroll
        for (int jj = 0; jj < 4; jj++)
            oH[ob + jj] = f2b(oa[i][jj] * invl);
    }
}

extern "C" void kernel_launch(void* const* d_in, const int* in_sizes, int n_in,
                              void* d_out, int out_size, void* d_ws, size_t ws_size,
                              hipStream_t stream)
{
    const int*  x    = (const int*) d_in[0];
    const void* tok  = d_in[1];
    const void* pos  = d_in[2];
    const void* Wq   = d_in[3];
    const void* Wk   = d_in[4];
    const void* Wv   = d_in[5];
    const void* Wo   = d_in[6];
    const void* bo   = d_in[7];
    const void* ln1g = d_in[8];
    const void* ln1b = d_in[9];
    const void* ln2g = d_in[10];
    const void* ln2b = d_in[11];
    const void* W1   = d_in[12];
    const void* b1   = d_in[13];
    const void* W2   = d_in[14];
    const void* b2   = d_in[15];
    const void* lnfg = d_in[16];
    const void* lnfb = d_in[17];
    const void* Wh   = d_in[18];
    const void* bh   = d_in[19];

    float* ws = (float*)d_ws;
    int* flag = (int*)ws;
    const size_t MC = (size_t)N_M * N_EMB;           // 1,572,864
    float*   h    = ws + 64;                         // MC fp32
    ushortT* aH   = (ushortT*)(h + MC);              // MC bf16 (ln out / attn out)
    float*   qkvF = (float*)(aH + MC);               // 3*MC fp32; ffh (4*MC bf16) aliases
    ushortT* ffh  = (ushortT*)qkvF;
    ushortT* wstg = (ushortT*)(qkvF + 3 * MC);       // weight staging
    ushortT* wsQ  = wstg;                            // 2304*768
    ushortT* wsO  = wsQ  + (size_t)QKVW * N_EMB;     // 768*768
    ushortT* wsF1 = wsO  + (size_t)N_EMB * N_EMB;    // 3072*768
    ushortT* wsF2 = wsF1 + (size_t)N_EMB * 4 * N_EMB;// 768*3072
    // head weight staging reuses wstg base (layer weights dead by then): 32000*768

    detect_kernel<<<1, 256, 0, stream>>>((const unsigned int*)tok, flag);
    embed_kernel<<<(int)((MC + 255) / 256), 256, 0, stream>>>(x, tok, pos, flag, h);

    const int nb_bias = (int)((MC + 255) / 256);

    for (int l = 0; l < N_LAYER; l++) {
        ln_kernel<<<N_M, 256, 0, stream>>>(h, ln1g, ln1b, (size_t)l * N_EMB, flag, aH);

        conv_qkv<<<dim3(QKVW / 32, N_EMB / 32), 256, 0, stream>>>(
            Wq, Wk, Wv, (size_t)l * N_HEAD * N_EMB * HEAD_D, flag, wsQ);
        gemm_mfma<64, 128><<<dim3(N_M / 64, QKVW / 128), 256, 0, stream>>>(
            aH, wsQ, nullptr, 0, qkvF, nullptr, nullptr, nullptr,
            flag, QKVW, N_EMB, N_EMB, 0);

        attn_kernel<<<dim3(N_T / 64, N_HEAD, N_B), 256, 0, stream>>>(qkvF, aH);

        conv_t<<<dim3(N_EMB / 32, N_EMB / 32), 256, 0, stream>>>(
            Wo, (size_t)l * N_EMB * N_EMB, flag, wsO, N_EMB, N_EMB);
        addbias_kernel<<<nb_bias, 256, 0, stream>>>(h, bo, (size_t)l * N_EMB, flag);
        gemm_mfma<64, 128><<<dim3(N_M / 64, N_EMB / 128, 3), 256, 0, stream>>>(
            aH, wsO, nullptr, 0, nullptr, nullptr, nullptr, h,
            flag, N_EMB, N_EMB, N_EMB / 3, 0);

        ln_kernel<<<N_M, 256, 0, stream>>>(h, ln2g, ln2b, (size_t)l * N_EMB, flag, aH);

        conv_t<<<dim3(4 * N_EMB / 32, N_EMB / 32), 256, 0, stream>>>(
            W1, (size_t)l * N_EMB * 4 * N_EMB, flag, wsF1, N_EMB, 4 * N_EMB);
        gemm_mfma<64, 128><<<dim3(N_M / 64, 4 * N_EMB / 128), 256, 0, stream>>>(
            aH, wsF1, b1, (size_t)l * 4 * N_EMB, nullptr, ffh, nullptr, nullptr,
            flag, 4 * N_EMB, N_EMB, N_EMB, 1);

        conv_t<<<dim3(N_EMB / 32, 4 * N_EMB / 32), 256, 0, stream>>>(
            W2, (size_t)l * 4 * N_EMB * N_EMB, flag, wsF2, 4 * N_EMB, N_EMB);
        addbias_kernel<<<nb_bias, 256, 0, stream>>>(h, b2, (size_t)l * N_EMB, flag);
        gemm_mfma<64, 128><<<dim3(N_M / 64, N_EMB / 128, 4), 256, 0, stream>>>(
            ffh, wsF2, nullptr, 0, nullptr, nullptr, nullptr, h,
            flag, N_EMB, 4 * N_EMB, N_EMB, 0);
    }

    ln_kernel<<<N_M, 256, 0, stream>>>(h, lnfg, lnfb, 0, flag, aH);

    conv_t<<<dim3(N_VOCAB / 32, N_EMB / 32), 256, 0, stream>>>(
        Wh, 0, flag, wstg, N_EMB, N_VOCAB);
    gemm_mfma<128, 128><<<dim3(N_M / 128, N_VOCAB / 128), 256, 0, stream>>>(
        aH, wstg, bh, 0, nullptr, nullptr, d_out, nullptr,
        flag, N_VOCAB, N_EMB, N_EMB, 0);
}